// Round 8
// baseline (262.321 us; speedup 1.0000x reference)
//
#include <hip/hip_runtime.h>
#include <hip/hip_bf16.h>

#define NF 128   // F_IN == F_OUT == 128

typedef __attribute__((ext_vector_type(8))) short short8;   // 8 bf16 = 4 VGPRs (MFMA A/B frag)
typedef __attribute__((ext_vector_type(4))) float f32x4;    // MFMA C/D frag

__device__ __forceinline__ ushort f2bf(float f) {
    union { __hip_bfloat16 h; ushort u; } c;
    c.h = __float2bfloat16(f);
    return c.u;
}
__device__ __forceinline__ float bf_lo(uint u) { return __uint_as_float(u << 16); }
__device__ __forceinline__ float bf_hi(uint u) { return __uint_as_float(u & 0xffff0000u); }

#define EPB 4096     // edges per sort block
#define CAP 12800    // slack capacity per 512-node bin in pairS (mean 8163 + 51 sigma)

// ---------------------------------------------------------------------------
// K1 cvtsort: fused {cvt x/W1/W2 -> bf16} + {block-local counting sort of EPB
// edges into per-bin slack regions of pairS}. bin base = bin*CAP, allocation
// via binOff atomics (zeroed before). After K1, binOff[b] == bin b edge count.
// ---------------------------------------------------------------------------
__global__ void cvtsort_kernel(const float* __restrict__ x, const float* __restrict__ W1,
                               const float* __restrict__ W2, ushort* __restrict__ xb,
                               ushort* __restrict__ W1b, ushort* __restrict__ W2b,
                               const int* __restrict__ ei, int* __restrict__ binOff,
                               uint2* __restrict__ pairS, int nx4, int nblkC, int E) {
    __shared__ uint2 sorted[EPB];   // 32 KB
    __shared__ int lcnt[256];
    __shared__ int lofs[256];
    __shared__ int lcur[256];
    __shared__ int gdelta[256];
    int t = threadIdx.x;
    int blk = blockIdx.x;
    if (blk < nblkC) {
        lcnt[t] = 0;
        lcur[t] = 0;
        __syncthreads();
        int base = blk * EPB;
        int rows[EPB / 256], cols[EPB / 256];
#pragma unroll
        for (int it = 0; it < EPB / 256; it++) {
            int e = base + it * 256 + t;
            rows[it] = (e < E) ? ei[e] : -1;
            cols[it] = (e < E) ? ei[E + e] : 0;
            if (rows[it] >= 0) atomicAdd(&lcnt[rows[it] >> 9], 1);
        }
        __syncthreads();
        int v = lcnt[t];
        lofs[t] = v;
        __syncthreads();
#pragma unroll
        for (int off = 1; off < 256; off <<= 1) {
            int u = (t >= off) ? lofs[t - off] : 0;
            __syncthreads();
            lofs[t] += u;
            __syncthreads();
        }
        int myOfs = lofs[t] - v;
        int g = v ? atomicAdd(&binOff[t], v) : 0;
        __syncthreads();
        lofs[t] = myOfs;
        gdelta[t] = t * CAP + g - myOfs;
        __syncthreads();
#pragma unroll
        for (int it = 0; it < EPB / 256; it++) {
            if (rows[it] >= 0) {
                int b = rows[it] >> 9;
                int p = lofs[b] + atomicAdd(&lcur[b], 1);
                sorted[p] = make_uint2((uint)rows[it], (uint)cols[it]);
            }
        }
        __syncthreads();
        int nvalid = min(EPB, E - base);
        for (int i = t; i < nvalid; i += 256) {
            uint2 pr = sorted[i];
            pairS[gdelta[pr.x >> 9] + i] = pr;
        }
    }
    // ---- streaming cvt part (all blocks) ----
    int gid = blk * 256 + t;
    const float* src;
    ushort* dst;
    int idx;
    if (gid < nx4) { src = x; dst = xb; idx = gid; }
    else if (gid < nx4 + 4096) { src = W1; dst = W1b; idx = gid - nx4; }
    else if (gid < nx4 + 8192) { src = W2; dst = W2b; idx = gid - nx4 - 4096; }
    else return;
    float4 v = reinterpret_cast<const float4*>(src)[idx];
    ushort4 o;
    o.x = f2bf(v.x); o.y = f2bf(v.y); o.z = f2bf(v.z); o.w = f2bf(v.w);
    reinterpret_cast<ushort4*>(dst)[idx] = o;
}

// ---------------------------------------------------------------------------
// passDE: per-bin node histogram + LDS scan -> rowptr, LDS-cursor fill -> adj.
// ---------------------------------------------------------------------------
__global__ void passDE_kernel(const uint2* __restrict__ pairS, const int* __restrict__ binOff,
                              int* __restrict__ rowptr, int* __restrict__ adj, int N, int E) {
    __shared__ int hist[512];
    __shared__ int s2[256];
    __shared__ int cur[512];
    int t = threadIdx.x;
    int b = blockIdx.x;
    hist[t] = 0;
    hist[t + 256] = 0;
    s2[t] = (t < b) ? binOff[t] : 0;
    __syncthreads();
#pragma unroll
    for (int off = 128; off > 0; off >>= 1) {
        if (t < off) s2[t] += s2[t + off];
        __syncthreads();
    }
    int base = s2[0];
    int cnt = binOff[b];
    size_t pbase = (size_t)b * CAP;
    __syncthreads();
    for (int i = t; i < cnt; i += 256)
        atomicAdd(&hist[pairS[pbase + i].x & 511], 1);
    __syncthreads();
    int h0 = hist[2 * t], h1 = hist[2 * t + 1];
    s2[t] = h0 + h1;
    __syncthreads();
#pragma unroll
    for (int off = 1; off < 256; off <<= 1) {
        int u = (t >= off) ? s2[t - off] : 0;
        __syncthreads();
        s2[t] += u;
        __syncthreads();
    }
    int e0 = base + s2[t] - (h0 + h1);
    int e1 = e0 + h0;
    int g0 = b * 512 + 2 * t;
    if (g0 < N) rowptr[g0] = e0;
    if (g0 + 1 < N) rowptr[g0 + 1] = e1;
    if (t == 0 && b == gridDim.x - 1) rowptr[N] = E;
    cur[2 * t] = e0;
    cur[2 * t + 1] = e1;
    __syncthreads();
    for (int i = t; i < cnt; i += 256) {
        uint2 p = pairS[pbase + i];
        int slot = atomicAdd(&cur[p.x & 511], 1);
        adj[slot] = (int)p.y;
    }
}

// ---------------------------------------------------------------------------
// bf16 MFMA GEMM, 128x128 tile, 4 waves (2x2), wave = 4x4 of 16x16x32 tiles.
// MODE 0 (fused gather-GEMM): A-tile is gathered IN-PROLOGUE from xb via
//   rowptr/adj (16 lanes/node, 8-unrolled edge loop -> bf16 pack -> As LDS;
//   no aggb array). h -> LDS tile -> coalesced uint4 stores to hb; fused BN
//   sum/sumsq.
// MODE 1: BN finalize in-prologue; A = relu(hb*scale+shift); result -> LDS
//   fp32 tile -> coalesced float4 stores to out.
// ---------------------------------------------------------------------------
#define ACCV(v)                                                   \
    a0 += bf_lo((v).x); a1 += bf_hi((v).x);                       \
    a2 += bf_lo((v).y); a3 += bf_hi((v).y);                       \
    a4 += bf_lo((v).z); a5 += bf_hi((v).z);                       \
    a6 += bf_lo((v).w); a7 += bf_hi((v).w);

template <int MODE>
__global__ __launch_bounds__(256) void mgemm_kernel(
    const uint4* __restrict__ xb4, const int* __restrict__ rowptr,
    const int* __restrict__ adj, const float* __restrict__ eps,
    const ushort* __restrict__ Wb, const float* __restrict__ bias,
    float* __restrict__ out, ushort* __restrict__ hb, float* __restrict__ stats,
    const float* __restrict__ gamma, const float* __restrict__ beta, int N) {
    __shared__ __align__(16) ushort smem[2 * 128 * 136];   // As | Bs (69632 B)
    __shared__ float redS[256];
    __shared__ float redQ[256];
    __shared__ float scL[128];
    __shared__ float shL[128];
    ushort* As = smem;
    ushort* Bs = smem + 128 * 136;

    const int t = threadIdx.x;
    const int row0 = blockIdx.x * 128;
    const int r16 = t >> 4;
    const int c8 = (t & 15) * 8;
    const int lg = t & 15;

    if (MODE == 1 && t < 128) {
        float inv_n = 1.0f / (float)N;
        float mean = stats[t] * inv_n;
        float var = fmaxf(stats[128 + t] * inv_n - mean * mean, 0.0f);
        float s = gamma[t] * rsqrtf(var + 1e-5f);
        scL[t] = s;
        shL[t] = beta[t] - mean * s;
    }
    if (MODE == 1) __syncthreads();

    if (MODE == 0) {
        // ---- fused gather: fill As[128][136] with agg rows of this tile ----
        float es = 1.0f + eps[0];
#pragma unroll 1
        for (int sub = 0; sub < 8; sub++) {
            int row = sub * 16 + r16;
            int gr = row0 + row;
            float a0 = 0.f, a1 = 0.f, a2 = 0.f, a3 = 0.f;
            float a4 = 0.f, a5 = 0.f, a6 = 0.f, a7 = 0.f;
            if (gr < N) {
                uint4 u = xb4[(size_t)gr * 16 + lg];
                a0 = bf_lo(u.x) * es; a1 = bf_hi(u.x) * es;
                a2 = bf_lo(u.y) * es; a3 = bf_hi(u.y) * es;
                a4 = bf_lo(u.z) * es; a5 = bf_hi(u.z) * es;
                a6 = bf_lo(u.w) * es; a7 = bf_hi(u.w) * es;
                int j = rowptr[gr], end = rowptr[gr + 1];
                for (; j + 8 <= end; j += 8) {
                    int c0 = adj[j],     c1 = adj[j + 1], c2 = adj[j + 2], c3 = adj[j + 3];
                    int c4 = adj[j + 4], c5 = adj[j + 5], c6 = adj[j + 6], c7 = adj[j + 7];
                    uint4 v0 = xb4[(size_t)c0 * 16 + lg];
                    uint4 v1 = xb4[(size_t)c1 * 16 + lg];
                    uint4 v2 = xb4[(size_t)c2 * 16 + lg];
                    uint4 v3 = xb4[(size_t)c3 * 16 + lg];
                    uint4 v4 = xb4[(size_t)c4 * 16 + lg];
                    uint4 v5 = xb4[(size_t)c5 * 16 + lg];
                    uint4 v6 = xb4[(size_t)c6 * 16 + lg];
                    uint4 v7 = xb4[(size_t)c7 * 16 + lg];
                    ACCV(v0) ACCV(v1) ACCV(v2) ACCV(v3)
                    ACCV(v4) ACCV(v5) ACCV(v6) ACCV(v7)
                }
                if (j + 4 <= end) {
                    int c0 = adj[j], c1 = adj[j + 1], c2 = adj[j + 2], c3 = adj[j + 3];
                    uint4 v0 = xb4[(size_t)c0 * 16 + lg];
                    uint4 v1 = xb4[(size_t)c1 * 16 + lg];
                    uint4 v2 = xb4[(size_t)c2 * 16 + lg];
                    uint4 v3 = xb4[(size_t)c3 * 16 + lg];
                    ACCV(v0) ACCV(v1) ACCV(v2) ACCV(v3)
                    j += 4;
                }
                if (j + 2 <= end) {
                    int c0 = adj[j], c1 = adj[j + 1];
                    uint4 v0 = xb4[(size_t)c0 * 16 + lg];
                    uint4 v1 = xb4[(size_t)c1 * 16 + lg];
                    ACCV(v0) ACCV(v1)
                    j += 2;
                }
                if (j < end) {
                    uint4 v0 = xb4[(size_t)adj[j] * 16 + lg];
                    ACCV(v0)
                }
            }
            uint4 o;
            o.x = (uint)f2bf(a0) | ((uint)f2bf(a1) << 16);
            o.y = (uint)f2bf(a2) | ((uint)f2bf(a3) << 16);
            o.z = (uint)f2bf(a4) | ((uint)f2bf(a5) << 16);
            o.w = (uint)f2bf(a6) | ((uint)f2bf(a7) << 16);
            *reinterpret_cast<uint4*>(&As[row * 136 + c8]) = o;
        }
        // ---- B tile (W1) ----
#pragma unroll
        for (int it = 0; it < 8; it++) {
            int row = it * 16 + r16;
            uint4 w = *reinterpret_cast<const uint4*>(Wb + row * NF + c8);
            *reinterpret_cast<uint4*>(&Bs[row * 136 + c8]) = w;
        }
    } else {
        float sc[8], sh[8];
#pragma unroll
        for (int i = 0; i < 8; i++) { sc[i] = scL[c8 + i]; sh[i] = shL[c8 + i]; }
#pragma unroll
        for (int it = 0; it < 8; it++) {
            int row = it * 16 + r16;
            int gr = row0 + row;
            uint4 v = make_uint4(0, 0, 0, 0);
            if (gr < N) v = *reinterpret_cast<const uint4*>(hb + (size_t)gr * NF + c8);
            float vv[8] = {bf_lo(v.x), bf_hi(v.x), bf_lo(v.y), bf_hi(v.y),
                           bf_lo(v.z), bf_hi(v.z), bf_lo(v.w), bf_hi(v.w)};
#pragma unroll
            for (int i = 0; i < 8; i++) vv[i] = fmaxf(vv[i] * sc[i] + sh[i], 0.0f);
            uint4 p;
            p.x = (uint)f2bf(vv[0]) | ((uint)f2bf(vv[1]) << 16);
            p.y = (uint)f2bf(vv[2]) | ((uint)f2bf(vv[3]) << 16);
            p.z = (uint)f2bf(vv[4]) | ((uint)f2bf(vv[5]) << 16);
            p.w = (uint)f2bf(vv[6]) | ((uint)f2bf(vv[7]) << 16);
            *reinterpret_cast<uint4*>(&As[row * 136 + c8]) = p;
            uint4 w = *reinterpret_cast<const uint4*>(Wb + row * NF + c8);
            *reinterpret_cast<uint4*>(&Bs[row * 136 + c8]) = w;
        }
    }
    __syncthreads();

    const int wid = t >> 6;
    const int lane = t & 63;
    const int quad = lane >> 4;
    const int l16 = lane & 15;
    const int wm = wid >> 1;
    const int wn = wid & 1;

    f32x4 acc[4][4];
#pragma unroll
    for (int tm = 0; tm < 4; tm++)
#pragma unroll
        for (int tn = 0; tn < 4; tn++) acc[tm][tn] = (f32x4)(0.0f);

#pragma unroll
    for (int ks = 0; ks < 4; ks++) {
        short8 a[4], b[4];
#pragma unroll
        for (int tm = 0; tm < 4; tm++)
            a[tm] = *reinterpret_cast<const short8*>(
                &As[(wm * 64 + tm * 16 + l16) * 136 + ks * 32 + quad * 8]);
#pragma unroll
        for (int tn = 0; tn < 4; tn++)
            b[tn] = *reinterpret_cast<const short8*>(
                &Bs[(wn * 64 + tn * 16 + l16) * 136 + ks * 32 + quad * 8]);
#pragma unroll
        for (int tm = 0; tm < 4; tm++)
#pragma unroll
            for (int tn = 0; tn < 4; tn++)
                acc[tm][tn] = __builtin_amdgcn_mfma_f32_16x16x32_bf16(a[tm], b[tn],
                                                                      acc[tm][tn], 0, 0, 0);
    }

    float bs[4];
#pragma unroll
    for (int tn = 0; tn < 4; tn++) bs[tn] = bias[wn * 64 + tn * 16 + l16];

    // As/Bs dead after MFMA; reuse as output staging tile.
    __syncthreads();
    ushort* htile = As;                                  // MODE 0: 128x128 bf16
    float* ftile = reinterpret_cast<float*>(smem);       // MODE 1: 128x128 f32

    float ssum[4] = {0.f, 0.f, 0.f, 0.f}, sq[4] = {0.f, 0.f, 0.f, 0.f};
#pragma unroll
    for (int tm = 0; tm < 4; tm++) {
        int rb = wm * 64 + tm * 16 + quad * 4;
#pragma unroll
        for (int reg = 0; reg < 4; reg++) {
            int gr = row0 + rb + reg;
            bool ok = gr < N;
#pragma unroll
            for (int tn = 0; tn < 4; tn++) {
                int col = wn * 64 + tn * 16 + l16;
                float h = acc[tm][tn][reg] + bs[tn];
                if (MODE == 0) {
                    htile[(rb + reg) * 128 + col] = f2bf(h);
                    if (ok) { ssum[tn] += h; sq[tn] += h * h; }
                } else {
                    ftile[(rb + reg) * 128 + col] = h;
                }
            }
        }
    }
    __syncthreads();

    if (MODE == 0) {
        for (int i = t; i < 2048; i += 256) {
            int row = i >> 4;
            int gr = row0 + row;
            if (gr < N)
                *reinterpret_cast<uint4*>(hb + (size_t)gr * NF + (i & 15) * 8) =
                    *reinterpret_cast<const uint4*>(htile + row * 128 + (i & 15) * 8);
        }
    } else {
        for (int i = t; i < 4096; i += 256) {
            int row = i >> 5;
            int gr = row0 + row;
            if (gr < N)
                *reinterpret_cast<float4*>(out + (size_t)gr * NF + (i & 31) * 4) =
                    *reinterpret_cast<const float4*>(ftile + row * 128 + (i & 31) * 4);
        }
    }

    if (MODE == 0) {
#pragma unroll
        for (int tn = 0; tn < 4; tn++) {
            float s = ssum[tn], q = sq[tn];
            s += __shfl_xor(s, 16); s += __shfl_xor(s, 32);
            q += __shfl_xor(q, 16); q += __shfl_xor(q, 32);
            if (quad == 0) {
                int c = wn * 64 + tn * 16 + l16;
                redS[wm * 128 + c] = s;
                redQ[wm * 128 + c] = q;
            }
        }
        __syncthreads();
        if (t < 128) {
            unsafeAtomicAdd(&stats[t], redS[t] + redS[128 + t]);
            unsafeAtomicAdd(&stats[128 + t], redQ[t] + redQ[128 + t]);
        }
    }
}

extern "C" void kernel_launch(void* const* d_in, const int* in_sizes, int n_in,
                              void* d_out, int out_size, void* d_ws, size_t ws_size,
                              hipStream_t stream) {
    const float* x     = (const float*)d_in[0];
    const int* ei      = (const int*)d_in[1];  // [2, E], int32 per harness
    const float* eps   = (const float*)d_in[2];
    const float* W1    = (const float*)d_in[3];
    const float* b1    = (const float*)d_in[4];
    const float* gamma = (const float*)d_in[5];
    const float* beta  = (const float*)d_in[6];
    const float* W2    = (const float*)d_in[7];
    const float* b2    = (const float*)d_in[8];
    float* out         = (float*)d_out;

    const int N = in_sizes[0] / NF;   // 100000
    const int E = in_sizes[1] / 2;    // 1600000

    const int NB = (N + 511) >> 9;            // bins (196)
    const int nblkC = (E + EPB - 1) / EPB;    // sort blocks (391)

    // workspace layout (~58 MB)
    // xb stays LIVE through fused mgemm0 (gather reads it), so hb moved to
    // the second region (pairS alias, dead after passDE). No aggb array.
    ushort* xb     = (ushort*)d_ws;                 // N*128 bf16 (live to mgemm0)
    ushort* hb     = xb + (size_t)N * NF;           // N*128 bf16 (pairS alias, 20.1<25.6MB)
    ushort* W1b    = hb + (size_t)N * NF;           // 16384 bf16
    ushort* W2b    = W1b + NF * NF;                 // 16384 bf16
    float*  stats  = (float*)(W2b + NF * NF);       // 512 f32
    int*    binOff = (int*)(stats + 512);           // 256 (cursor -> bin counts)
    int*    rowptr = binOff + 256;                  // N+1
    int*    adj    = rowptr + (N + 1);              // E
    uint2*  pairS  = (uint2*)hb;                    // 196*CAP pairs (dead before hb born)

    // zero stats(512f) + binOff(256) = 3 KB contiguous
    (void)hipMemsetAsync(stats, 0, 3072, stream);

    int nx4 = N * 32;
    int cvtBlocks = (nx4 + 8192 + 255) / 256;       // 12533 >= nblkC
    cvtsort_kernel<<<cvtBlocks, 256, 0, stream>>>(x, W1, W2, xb, W1b, W2b, ei, binOff,
                                                  pairS, nx4, nblkC, E);
    passDE_kernel<<<NB, 256, 0, stream>>>(pairS, binOff, rowptr, adj, N, E);

    int gblocks = (N + 127) / 128;
    mgemm_kernel<0><<<gblocks, 256, 0, stream>>>((const uint4*)xb, rowptr, adj, eps,
                                                 W1b, b1, out, hb, stats,
                                                 nullptr, nullptr, N);
    mgemm_kernel<1><<<gblocks, 256, 0, stream>>>(nullptr, nullptr, nullptr, nullptr,
                                                 W2b, b2, out, hb, stats,
                                                 gamma, beta, N);
}

// Round 10
// 255.001 us; speedup vs baseline: 1.0287x; 1.0287x over previous
//
#include <hip/hip_runtime.h>
#include <hip/hip_bf16.h>

#define NF 128   // F_IN == F_OUT == 128

typedef __attribute__((ext_vector_type(8))) short short8;   // 8 bf16 = 4 VGPRs (MFMA A/B frag)
typedef __attribute__((ext_vector_type(4))) float f32x4;    // MFMA C/D frag

__device__ __forceinline__ ushort f2bf(float f) {
    union { __hip_bfloat16 h; ushort u; } c;
    c.h = __float2bfloat16(f);
    return c.u;
}
__device__ __forceinline__ float bf_lo(uint u) { return __uint_as_float(u << 16); }
__device__ __forceinline__ float bf_hi(uint u) { return __uint_as_float(u & 0xffff0000u); }

#define EPB 4096     // edges per sort block
#define CAP 12800    // slack capacity per 512-node bin in pairS (mean 8163 + 51 sigma)

// pair encoding: 26 bits = (lrow:9 << 17) | (col:17).  lrow = row & 511,
// bin = row >> 9 (196 bins).  col < 131072 required (N = 100000 ok).

// ---------------------------------------------------------------------------
// K1 cvtsort: fused {cvt x/W1/W2 -> bf16} + {block-local counting sort of EPB
// edges into per-bin slack regions of pairS}. bin base = bin*CAP, allocation
// via binOff atomics (zeroed before). After K1, binOff[b] == bin b edge count.
// Scans are wave64-shfl based: 5 barriers total (was ~20).
// ---------------------------------------------------------------------------
__global__ void cvtsort_kernel(const float* __restrict__ x, const float* __restrict__ W1,
                               const float* __restrict__ W2, ushort* __restrict__ xb,
                               ushort* __restrict__ W1b, ushort* __restrict__ W2b,
                               const int* __restrict__ ei, int* __restrict__ binOff,
                               uint* __restrict__ pairS, int nx4, int nblkC, int E) {
    __shared__ uint sorted[EPB];       // 16 KB (packed pairs)
    __shared__ uchar binOf[EPB];       // 4 KB (bin of sorted[i], for drain)
    __shared__ int lcnt[256];
    __shared__ int lofs[256];
    __shared__ int lcur[256];
    __shared__ int gdelta[256];
    __shared__ int wsum[4];
    int t = threadIdx.x;
    int blk = blockIdx.x;
    if (blk < nblkC) {
        lcnt[t] = 0;
        lcur[t] = 0;
        __syncthreads();                                   // B1
        int base = blk * EPB;
        int bn[EPB / 256];
        uint pk[EPB / 256];
#pragma unroll
        for (int it = 0; it < EPB / 256; it++) {
            int e = base + it * 256 + t;
            bn[it] = -1;
            pk[it] = 0;
            if (e < E) {
                int r = ei[e];
                int c = ei[E + e];
                bn[it] = r >> 9;
                pk[it] = ((uint)(r & 511) << 17) | (uint)c;
                atomicAdd(&lcnt[bn[it]], 1);
            }
        }
        __syncthreads();                                   // B2
        int v = lcnt[t];
        int lane = t & 63, w = t >> 6;
        int sv = v;
#pragma unroll
        for (int d = 1; d < 64; d <<= 1) {
            int n = __shfl_up(sv, d, 64);
            if (lane >= d) sv += n;
        }
        if (lane == 63) wsum[w] = sv;
        __syncthreads();                                   // B3
        int wpre = 0;
#pragma unroll
        for (int i = 0; i < 3; i++)
            if (i < w) wpre += wsum[i];
        int myOfs = sv + wpre - v;                          // exclusive prefix over 256 bins
        int g = v ? atomicAdd(&binOff[t], v) : 0;
        lofs[t] = myOfs;
        gdelta[t] = t * CAP + g - myOfs;
        __syncthreads();                                   // B4
#pragma unroll
        for (int it = 0; it < EPB / 256; it++) {
            if (bn[it] >= 0) {
                int b = bn[it];
                int p = lofs[b] + atomicAdd(&lcur[b], 1);
                sorted[p] = pk[it];
                binOf[p] = (uchar)b;
            }
        }
        __syncthreads();                                   // B5
        int nvalid = min(EPB, E - base);
        for (int i = t; i < nvalid; i += 256)
            pairS[gdelta[binOf[i]] + i] = sorted[i];
    }
    // ---- streaming cvt part (all blocks) ----
    int gid = blk * 256 + t;
    const float* src;
    ushort* dst;
    int idx;
    if (gid < nx4) { src = x; dst = xb; idx = gid; }
    else if (gid < nx4 + 4096) { src = W1; dst = W1b; idx = gid - nx4; }
    else if (gid < nx4 + 8192) { src = W2; dst = W2b; idx = gid - nx4 - 4096; }
    else return;
    float4 v = reinterpret_cast<const float4*>(src)[idx];
    ushort4 o;
    o.x = f2bf(v.x); o.y = f2bf(v.y); o.z = f2bf(v.z); o.w = f2bf(v.w);
    reinterpret_cast<ushort4*>(dst)[idx] = o;
}

// ---------------------------------------------------------------------------
// passDE: per-bin node histogram + wave-scan -> rowptr, LDS-cursor fill -> adj.
// Packed 4B pairs; 4 barriers (was ~26).
// ---------------------------------------------------------------------------
__global__ void passDE_kernel(const uint* __restrict__ pairS, const int* __restrict__ binOff,
                              int* __restrict__ rowptr, int* __restrict__ adj, int N, int E) {
    __shared__ int hist[512];
    __shared__ int cur[512];
    __shared__ int wsum[4];
    __shared__ int sBase;
    int t = threadIdx.x;
    int b = blockIdx.x;
    hist[t] = 0;
    hist[t + 256] = 0;
    if (t < 64) {                       // wave 0: base = sum binOff[0..b)
        int acc = 0;
        for (int i = t; i < b; i += 64) acc += binOff[i];
#pragma unroll
        for (int d = 32; d > 0; d >>= 1) acc += __shfl_xor(acc, d, 64);
        if (t == 0) sBase = acc;
    }
    __syncthreads();                                       // B1
    int base = sBase;
    int cnt = binOff[b];
    size_t pbase = (size_t)b * CAP;
    for (int i = t; i < cnt; i += 256)
        atomicAdd(&hist[pairS[pbase + i] >> 17], 1);
    __syncthreads();                                       // B2
    int h0 = hist[2 * t], h1 = hist[2 * t + 1];
    int v = h0 + h1;
    int lane = t & 63, w = t >> 6;
    int sv = v;
#pragma unroll
    for (int d = 1; d < 64; d <<= 1) {
        int n = __shfl_up(sv, d, 64);
        if (lane >= d) sv += n;
    }
    if (lane == 63) wsum[w] = sv;
    __syncthreads();                                       // B3
    int wpre = 0;
#pragma unroll
    for (int i = 0; i < 3; i++)
        if (i < w) wpre += wsum[i];
    int e0 = base + sv + wpre - v;
    int e1 = e0 + h0;
    int g0 = b * 512 + 2 * t;
    if (g0 < N) rowptr[g0] = e0;
    if (g0 + 1 < N) rowptr[g0 + 1] = e1;
    if (t == 0 && b == gridDim.x - 1) rowptr[N] = E;
    cur[2 * t] = e0;
    cur[2 * t + 1] = e1;
    __syncthreads();                                       // B4
    for (int i = t; i < cnt; i += 256) {
        uint p = pairS[pbase + i];
        int slot = atomicAdd(&cur[p >> 17], 1);
        adj[slot] = (int)(p & 0x1FFFF);
    }
}

// ---------------------------------------------------------------------------
// Gather-aggregate (exact R7 form): 16 lanes per node (uint4/lane -> 256B/row),
// 4 node streams per wave, edge loop unrolled x8 (+4/2/1 tail).
// aggb[node] = bf16( (1+eps)*x[node] + sum_j x[adj[j]] )   (fp32 accum)
// ---------------------------------------------------------------------------
#define ACCV(v)                                                   \
    a0 += bf_lo((v).x); a1 += bf_hi((v).x);                       \
    a2 += bf_lo((v).y); a3 += bf_hi((v).y);                       \
    a4 += bf_lo((v).z); a5 += bf_hi((v).z);                       \
    a6 += bf_lo((v).w); a7 += bf_hi((v).w);

__global__ void gather_kernel(const uint4* __restrict__ xb4, const int* __restrict__ rowptr,
                              const int* __restrict__ adj, const float* __restrict__ eps,
                              uint4* __restrict__ aggb4, int N) {
    int t = blockIdx.x * blockDim.x + threadIdx.x;
    int node = t >> 4;
    int lane = t & 15;
    if (node >= N) return;
    uint4 u = xb4[(size_t)node * 16 + lane];
    float s = 1.0f + eps[0];
    float a0 = bf_lo(u.x) * s, a1 = bf_hi(u.x) * s;
    float a2 = bf_lo(u.y) * s, a3 = bf_hi(u.y) * s;
    float a4 = bf_lo(u.z) * s, a5 = bf_hi(u.z) * s;
    float a6 = bf_lo(u.w) * s, a7 = bf_hi(u.w) * s;
    int j = rowptr[node], end = rowptr[node + 1];
    for (; j + 8 <= end; j += 8) {
        int c0 = adj[j],     c1 = adj[j + 1], c2 = adj[j + 2], c3 = adj[j + 3];
        int c4 = adj[j + 4], c5 = adj[j + 5], c6 = adj[j + 6], c7 = adj[j + 7];
        uint4 v0 = xb4[(size_t)c0 * 16 + lane];
        uint4 v1 = xb4[(size_t)c1 * 16 + lane];
        uint4 v2 = xb4[(size_t)c2 * 16 + lane];
        uint4 v3 = xb4[(size_t)c3 * 16 + lane];
        uint4 v4 = xb4[(size_t)c4 * 16 + lane];
        uint4 v5 = xb4[(size_t)c5 * 16 + lane];
        uint4 v6 = xb4[(size_t)c6 * 16 + lane];
        uint4 v7 = xb4[(size_t)c7 * 16 + lane];
        ACCV(v0) ACCV(v1) ACCV(v2) ACCV(v3)
        ACCV(v4) ACCV(v5) ACCV(v6) ACCV(v7)
    }
    if (j + 4 <= end) {
        int c0 = adj[j], c1 = adj[j + 1], c2 = adj[j + 2], c3 = adj[j + 3];
        uint4 v0 = xb4[(size_t)c0 * 16 + lane];
        uint4 v1 = xb4[(size_t)c1 * 16 + lane];
        uint4 v2 = xb4[(size_t)c2 * 16 + lane];
        uint4 v3 = xb4[(size_t)c3 * 16 + lane];
        ACCV(v0) ACCV(v1) ACCV(v2) ACCV(v3)
        j += 4;
    }
    if (j + 2 <= end) {
        int c0 = adj[j], c1 = adj[j + 1];
        uint4 v0 = xb4[(size_t)c0 * 16 + lane];
        uint4 v1 = xb4[(size_t)c1 * 16 + lane];
        ACCV(v0) ACCV(v1)
        j += 2;
    }
    if (j < end) {
        uint4 v0 = xb4[(size_t)adj[j] * 16 + lane];
        ACCV(v0)
    }
    uint4 o;
    o.x = (uint)f2bf(a0) | ((uint)f2bf(a1) << 16);
    o.y = (uint)f2bf(a2) | ((uint)f2bf(a3) << 16);
    o.z = (uint)f2bf(a4) | ((uint)f2bf(a5) << 16);
    o.w = (uint)f2bf(a6) | ((uint)f2bf(a7) << 16);
    aggb4[(size_t)node * 16 + lane] = o;
}

// ---------------------------------------------------------------------------
// bf16 MFMA GEMM (exact R7 form): 128x128 tile, 4 waves (2x2), wave = 4x4 of
// 16x16x32 tiles.  MODE 0: A = aggb; h -> LDS tile -> coalesced uint4 stores
// to hb; fused BN sum/sumsq.  MODE 1: BN finalize in-prologue; A =
// relu(hb*scale+shift); result -> LDS fp32 tile -> coalesced float4 stores.
// ---------------------------------------------------------------------------
template <int MODE>
__global__ __launch_bounds__(256) void mgemm_kernel(
    const ushort* __restrict__ Ab, const ushort* __restrict__ Wb,
    const float* __restrict__ bias, float* __restrict__ out,
    ushort* __restrict__ hb, float* __restrict__ stats,
    const float* __restrict__ gamma, const float* __restrict__ beta, int N) {
    __shared__ __align__(16) ushort smem[2 * 128 * 136];   // As | Bs (69632 B)
    __shared__ float redS[256];
    __shared__ float redQ[256];
    __shared__ float scL[128];
    __shared__ float shL[128];
    ushort* As = smem;
    ushort* Bs = smem + 128 * 136;

    const int t = threadIdx.x;
    const int row0 = blockIdx.x * 128;
    const int r16 = t >> 4;
    const int c8 = (t & 15) * 8;

    if (MODE == 1 && t < 128) {
        float inv_n = 1.0f / (float)N;
        float mean = stats[t] * inv_n;
        float var = fmaxf(stats[128 + t] * inv_n - mean * mean, 0.0f);
        float s = gamma[t] * rsqrtf(var + 1e-5f);
        scL[t] = s;
        shL[t] = beta[t] - mean * s;
    }
    if (MODE == 1) __syncthreads();

    float sc[8], sh[8];
    if (MODE == 1) {
#pragma unroll
        for (int i = 0; i < 8; i++) { sc[i] = scL[c8 + i]; sh[i] = shL[c8 + i]; }
    }

#pragma unroll
    for (int it = 0; it < 8; it++) {
        int row = it * 16 + r16;
        int gr = row0 + row;
        if (MODE == 0) {
            uint4 v = make_uint4(0, 0, 0, 0);
            if (gr < N) v = *reinterpret_cast<const uint4*>(Ab + (size_t)gr * NF + c8);
            *reinterpret_cast<uint4*>(&As[row * 136 + c8]) = v;
        } else {
            uint4 v = make_uint4(0, 0, 0, 0);
            if (gr < N) v = *reinterpret_cast<const uint4*>(hb + (size_t)gr * NF + c8);
            float vv[8] = {bf_lo(v.x), bf_hi(v.x), bf_lo(v.y), bf_hi(v.y),
                           bf_lo(v.z), bf_hi(v.z), bf_lo(v.w), bf_hi(v.w)};
#pragma unroll
            for (int i = 0; i < 8; i++) vv[i] = fmaxf(vv[i] * sc[i] + sh[i], 0.0f);
            uint4 p;
            p.x = (uint)f2bf(vv[0]) | ((uint)f2bf(vv[1]) << 16);
            p.y = (uint)f2bf(vv[2]) | ((uint)f2bf(vv[3]) << 16);
            p.z = (uint)f2bf(vv[4]) | ((uint)f2bf(vv[5]) << 16);
            p.w = (uint)f2bf(vv[6]) | ((uint)f2bf(vv[7]) << 16);
            *reinterpret_cast<uint4*>(&As[row * 136 + c8]) = p;
        }
        uint4 w = *reinterpret_cast<const uint4*>(Wb + row * NF + c8);
        *reinterpret_cast<uint4*>(&Bs[row * 136 + c8]) = w;
    }
    __syncthreads();

    const int wid = t >> 6;
    const int lane = t & 63;
    const int quad = lane >> 4;
    const int l16 = lane & 15;
    const int wm = wid >> 1;
    const int wn = wid & 1;

    f32x4 acc[4][4];
#pragma unroll
    for (int tm = 0; tm < 4; tm++)
#pragma unroll
        for (int tn = 0; tn < 4; tn++) acc[tm][tn] = (f32x4)(0.0f);

#pragma unroll
    for (int ks = 0; ks < 4; ks++) {
        short8 a[4], b[4];
#pragma unroll
        for (int tm = 0; tm < 4; tm++)
            a[tm] = *reinterpret_cast<const short8*>(
                &As[(wm * 64 + tm * 16 + l16) * 136 + ks * 32 + quad * 8]);
#pragma unroll
        for (int tn = 0; tn < 4; tn++)
            b[tn] = *reinterpret_cast<const short8*>(
                &Bs[(wn * 64 + tn * 16 + l16) * 136 + ks * 32 + quad * 8]);
#pragma unroll
        for (int tm = 0; tm < 4; tm++)
#pragma unroll
            for (int tn = 0; tn < 4; tn++)
                acc[tm][tn] = __builtin_amdgcn_mfma_f32_16x16x32_bf16(a[tm], b[tn],
                                                                      acc[tm][tn], 0, 0, 0);
    }

    float bs[4];
#pragma unroll
    for (int tn = 0; tn < 4; tn++) bs[tn] = bias[wn * 64 + tn * 16 + l16];

    // As/Bs dead after MFMA; reuse as output staging tile.
    __syncthreads();
    ushort* htile = As;                                  // MODE 0: 128x128 bf16
    float* ftile = reinterpret_cast<float*>(smem);       // MODE 1: 128x128 f32

    float ssum[4] = {0.f, 0.f, 0.f, 0.f}, sq[4] = {0.f, 0.f, 0.f, 0.f};
#pragma unroll
    for (int tm = 0; tm < 4; tm++) {
        int rb = wm * 64 + tm * 16 + quad * 4;
#pragma unroll
        for (int reg = 0; reg < 4; reg++) {
            int gr = row0 + rb + reg;
            bool ok = gr < N;
#pragma unroll
            for (int tn = 0; tn < 4; tn++) {
                int col = wn * 64 + tn * 16 + l16;
                float h = acc[tm][tn][reg] + bs[tn];
                if (MODE == 0) {
                    htile[(rb + reg) * 128 + col] = f2bf(h);
                    if (ok) { ssum[tn] += h; sq[tn] += h * h; }
                } else {
                    ftile[(rb + reg) * 128 + col] = h;
                }
            }
        }
    }
    __syncthreads();

    if (MODE == 0) {
        for (int i = t; i < 2048; i += 256) {
            int row = i >> 4;
            int gr = row0 + row;
            if (gr < N)
                *reinterpret_cast<uint4*>(hb + (size_t)gr * NF + (i & 15) * 8) =
                    *reinterpret_cast<const uint4*>(htile + row * 128 + (i & 15) * 8);
        }
    } else {
        for (int i = t; i < 4096; i += 256) {
            int row = i >> 5;
            int gr = row0 + row;
            if (gr < N)
                *reinterpret_cast<float4*>(out + (size_t)gr * NF + (i & 31) * 4) =
                    *reinterpret_cast<const float4*>(ftile + row * 128 + (i & 31) * 4);
        }
    }

    if (MODE == 0) {
#pragma unroll
        for (int tn = 0; tn < 4; tn++) {
            float s = ssum[tn], q = sq[tn];
            s += __shfl_xor(s, 16); s += __shfl_xor(s, 32);
            q += __shfl_xor(q, 16); q += __shfl_xor(q, 32);
            if (quad == 0) {
                int c = wn * 64 + tn * 16 + l16;
                redS[wm * 128 + c] = s;
                redQ[wm * 128 + c] = q;
            }
        }
        __syncthreads();
        if (t < 128) {
            unsafeAtomicAdd(&stats[t], redS[t] + redS[128 + t]);
            unsafeAtomicAdd(&stats[128 + t], redQ[t] + redQ[128 + t]);
        }
    }
}

extern "C" void kernel_launch(void* const* d_in, const int* in_sizes, int n_in,
                              void* d_out, int out_size, void* d_ws, size_t ws_size,
                              hipStream_t stream) {
    const float* x     = (const float*)d_in[0];
    const int* ei      = (const int*)d_in[1];  // [2, E], int32 per harness
    const float* eps   = (const float*)d_in[2];
    const float* W1    = (const float*)d_in[3];
    const float* b1    = (const float*)d_in[4];
    const float* gamma = (const float*)d_in[5];
    const float* beta  = (const float*)d_in[6];
    const float* W2    = (const float*)d_in[7];
    const float* b2    = (const float*)d_in[8];
    float* out         = (float*)d_out;

    const int N = in_sizes[0] / NF;   // 100000
    const int E = in_sizes[1] / 2;    // 1600000

    const int NB = (N + 511) >> 9;            // bins (196)
    const int nblkC = (E + EPB - 1) / EPB;    // sort blocks (391)

    // workspace layout (~58 MB, R7 layout; pairS now packed uint = 10 MB)
    ushort* xb     = (ushort*)d_ws;                 // N*128 bf16 (becomes hb after gather)
    ushort* aggb   = xb + (size_t)N * NF;           // N*128 bf16 (pairS aliases)
    ushort* W1b    = aggb + (size_t)N * NF;         // 16384 bf16
    ushort* W2b    = W1b + NF * NF;                 // 16384 bf16
    float*  stats  = (float*)(W2b + NF * NF);       // 512 f32
    int*    binOff = (int*)(stats + 512);           // 256 (cursor -> bin counts)
    int*    rowptr = binOff + 256;                  // N+1
    int*    adj    = rowptr + (N + 1);              // E
    uint*   pairS  = (uint*)aggb;                   // 196*CAP packed pairs (dead after passDE)
    ushort* hb     = xb;                            // xb dead after gather

    // zero stats(512f) + binOff(256) = 3 KB contiguous
    (void)hipMemsetAsync(stats, 0, 3072, stream);

    int nx4 = N * 32;
    int cvtBlocks = (nx4 + 8192 + 255) / 256;       // 12533 >= nblkC
    cvtsort_kernel<<<cvtBlocks, 256, 0, stream>>>(x, W1, W2, xb, W1b, W2b, ei, binOff,
                                                  pairS, nx4, nblkC, E);
    passDE_kernel<<<NB, 256, 0, stream>>>(pairS, binOff, rowptr, adj, N, E);

    long long gt = (long long)N * 16;
    gather_kernel<<<(int)((gt + 255) / 256), 256, 0, stream>>>((const uint4*)xb, rowptr, adj,
                                                               eps, (uint4*)aggb, N);

    int gblocks = (N + 127) / 128;
    mgemm_kernel<0><<<gblocks, 256, 0, stream>>>(aggb, W1b, b1, out, hb, stats,
                                                 nullptr, nullptr, N);
    mgemm_kernel<1><<<gblocks, 256, 0, stream>>>(nullptr, W2b, b2, out, hb, stats,
                                                 gamma, beta, N);
}